// Round 3
// baseline (716.285 us; speedup 1.0000x reference)
//
#include <hip/hip_runtime.h>
#include <hip/hip_bf16.h>
#include <math.h>

// Problem constants
#define LL 512
#define BB 8
#define NN 32
#define DD 256
#define GH 128
#define AH 64

// LDS pitches (in elements)
#define PA 36      // ushort pitch: sAT[k<512][n<32]  (k-major, comb transposed, bf16)
#define PW1 132    // ushort pitch: sW[kk<64][j<128]  (gw1 chunk transposed, bf16)
#define PW2 68     // ushort pitch: sW[kk<64][j<64]   (aw1 chunk transposed, aliased)
#define PPART 33   // float pitch:  sPart[n<32][ty<32]

__device__ __forceinline__ float bf2f(unsigned short u) {
  return __uint_as_float(((unsigned int)u) << 16);
}
__device__ __forceinline__ unsigned short f2bf(float f) {
  union { __hip_bfloat16 h; unsigned short u; } cv;
  cv.h = __float2bfloat16(f);
  return cv.u;
}
__device__ __forceinline__ void bfquad(unsigned int u0, unsigned int u1, float* o) {
  o[0] = __uint_as_float(u0 << 16);
  o[1] = __uint_as_float(u0 & 0xffff0000u);
  o[2] = __uint_as_float(u1 << 16);
  o[3] = __uint_as_float(u1 & 0xffff0000u);
}

extern "C" __global__ __launch_bounds__(256, 2)
void dynfusion_kernel(const float* __restrict__ vert,
                      const float* __restrict__ horiz,
                      const int*   __restrict__ mask,   // [B][N][L] bool stored as int32
                      const float* __restrict__ gw1,    // [128][512]
                      const float* __restrict__ gb1,    // [128]
                      const float* __restrict__ gw2,    // [1][128]
                      const float* __restrict__ gb2,    // [1]
                      const float* __restrict__ aw1,    // [64][256]
                      const float* __restrict__ ab1,    // [64]
                      const float* __restrict__ aw2,    // [1][64]
                      const float* __restrict__ ab2,    // [1]
                      float* __restrict__ out)
{
  __shared__ __align__(16) unsigned short sAT[512 * PA];  // comb^T bf16; per_msg^T in k<256 half
  __shared__ __align__(16) unsigned short sW[64 * PW1];   // weight chunk (transposed, bf16)
  __shared__ float sPart[32 * PPART];
  __shared__ float sGw2[GH], sGb1[GH], sAb1[AH], sAw2[AH];
  __shared__ float sGate[NN], sAttn[NN], sScal[2];

  const int t  = threadIdx.x;
  const int lb = blockIdx.x;            // l*8 + b
  const int l  = lb >> 3;
  const int b  = lb & 7;
  const size_t msgBase = (size_t)lb * NN * DD;   // elem offset of (l,b,0,0) in [L,B,N,D]

  float* __restrict__ outF  = out;                         // fused  [L,B,D]
  float* __restrict__ outPM = out + 1048576;               // per_msg[L,B,N,D]
  float* __restrict__ outAT = out + 34603008;              // attn   [B,L,N]

  // ---------------- P0: stage small vectors + comb^T (as bf16) into LDS ----------------
  if (t < GH) { sGw2[t] = gw2[t]; sGb1[t] = gb1[t]; }
  if (t < AH) { sAb1[t] = ab1[t]; sAw2[t] = aw2[t]; }
  if (t == 0) { sScal[0] = gb2[0]; sScal[1] = ab2[0]; }

#pragma unroll
  for (int i = 0; i < 8; ++i) {
    int idx4 = i * 256 + t;                 // 2048 quads of 4 elems
    int n  = idx4 >> 6;
    int d0 = (idx4 & 63) << 2;
    float4 v4 = *reinterpret_cast<const float4*>(vert  + msgBase + n * DD + d0);
    float4 h4 = *reinterpret_cast<const float4*>(horiz + msgBase + n * DD + d0);
    sAT[(d0 + 0) * PA + n] = f2bf(v4.x);  sAT[(d0 + 1) * PA + n] = f2bf(v4.y);
    sAT[(d0 + 2) * PA + n] = f2bf(v4.z);  sAT[(d0 + 3) * PA + n] = f2bf(v4.w);
    sAT[(256 + d0 + 0) * PA + n] = f2bf(h4.x);  sAT[(256 + d0 + 1) * PA + n] = f2bf(h4.y);
    sAT[(256 + d0 + 2) * PA + n] = f2bf(h4.z);  sAT[(256 + d0 + 3) * PA + n] = f2bf(h4.w);
  }

  // ---------------- P1: gate GEMM  h[32][128] = comb[32][512] @ gw1^T ----------------
  const int tx = t & 7;           // n-group
  const int ty = t >> 3;          // j-group (32 groups)
  const int n0 = tx << 2;         // 4 rows
  const int j0 = ty << 2;         // 4 cols (gate)

  float acc[4][4];
#pragma unroll
  for (int a = 0; a < 4; ++a)
#pragma unroll
    for (int c = 0; c < 4; ++c) acc[a][c] = 0.0f;

  for (int kc = 0; kc < 8; ++kc) {
    __syncthreads();              // sW free (also covers P0 completion on kc==0)
#pragma unroll
    for (int i = 0; i < 8; ++i) {
      int idx4 = i * 256 + t;     // 2048 quads = 128 j x 64 kk
      int j   = idx4 >> 4;
      int kk0 = (idx4 & 15) << 2;
      float4 w4 = *reinterpret_cast<const float4*>(gw1 + j * 512 + kc * 64 + kk0);
      sW[(kk0 + 0) * PW1 + j] = f2bf(w4.x);  sW[(kk0 + 1) * PW1 + j] = f2bf(w4.y);
      sW[(kk0 + 2) * PW1 + j] = f2bf(w4.z);  sW[(kk0 + 3) * PW1 + j] = f2bf(w4.w);
    }
    __syncthreads();
#pragma unroll 8
    for (int kk = 0; kk < 64; ++kk) {
      int k = kc * 64 + kk;
      uint2 au = *reinterpret_cast<const uint2*>(&sAT[k * PA + n0]);
      uint2 wu = *reinterpret_cast<const uint2*>(&sW[kk * PW1 + j0]);
      float av[4], wv[4];
      bfquad(au.x, au.y, av);
      bfquad(wu.x, wu.y, wv);
#pragma unroll
      for (int ni = 0; ni < 4; ++ni)
#pragma unroll
        for (int ji = 0; ji < 4; ++ji) acc[ni][ji] += av[ni] * wv[ji];
    }
  }

  // gate epilogue: relu(h+gb1) dot gw2 -> partial per (n, ty)
  {
    float gp[4] = {0.f, 0.f, 0.f, 0.f};
#pragma unroll
    for (int ni = 0; ni < 4; ++ni)
#pragma unroll
      for (int ji = 0; ji < 4; ++ji) {
        float hv = fmaxf(acc[ni][ji] + sGb1[j0 + ji], 0.0f);
        gp[ni] += hv * sGw2[j0 + ji];
      }
#pragma unroll
    for (int ni = 0; ni < 4; ++ni) sPart[(n0 + ni) * PPART + ty] = gp[ni];
  }
  __syncthreads();
  if (t < 32) {
    float s = sScal[0];
#pragma unroll
    for (int q = 0; q < 32; ++q) s += sPart[t * PPART + q];
    sGate[t] = 1.0f / (1.0f + __expf(-s));
  }
  __syncthreads();

  // ---------------- P2: per_msg = gate*vert + (1-gate)*horiz ----------------
  // overwrite vert half of sAT with per_msg (bf16); store fp32 to global
#pragma unroll
  for (int i = 0; i < 16; ++i) {
    int idx2 = i * 256 + t;            // 4096 pairs
    int n  = idx2 >> 7;
    int d0 = (idx2 & 127) << 1;
    float g  = sGate[n];
    float v0 = bf2f(sAT[(d0    ) * PA + n]);
    float v1 = bf2f(sAT[(d0 + 1) * PA + n]);
    float h0 = bf2f(sAT[(256 + d0    ) * PA + n]);
    float h1 = bf2f(sAT[(256 + d0 + 1) * PA + n]);
    float p0 = h0 + g * (v0 - h0);
    float p1 = h1 + g * (v1 - h1);
    sAT[(d0    ) * PA + n] = f2bf(p0);
    sAT[(d0 + 1) * PA + n] = f2bf(p1);
    float2 pr; pr.x = p0; pr.y = p1;
    *reinterpret_cast<float2*>(outPM + msgBase + n * DD + d0) = pr;
  }
  __syncthreads();

  // ---------------- P3: scorer GEMM  a[32][64] = per_msg[32][256] @ aw1^T ----------------
  const int j0b = ty << 1;     // 2 cols (scorer), ty<32 covers 64
  float acc2[4][2];
#pragma unroll
  for (int a = 0; a < 4; ++a) { acc2[a][0] = 0.0f; acc2[a][1] = 0.0f; }

  for (int kc = 0; kc < 4; ++kc) {
#pragma unroll
    for (int i = 0; i < 4; ++i) {
      int idx4 = i * 256 + t;          // 1024 quads = 64 j x 64 kk
      int j   = idx4 >> 4;
      int kk0 = (idx4 & 15) << 2;
      float4 w4 = *reinterpret_cast<const float4*>(aw1 + j * 256 + kc * 64 + kk0);
      sW[(kk0 + 0) * PW2 + j] = f2bf(w4.x);  sW[(kk0 + 1) * PW2 + j] = f2bf(w4.y);
      sW[(kk0 + 2) * PW2 + j] = f2bf(w4.z);  sW[(kk0 + 3) * PW2 + j] = f2bf(w4.w);
    }
    __syncthreads();
#pragma unroll 8
    for (int kk = 0; kk < 64; ++kk) {
      int k = kc * 64 + kk;
      uint2 au = *reinterpret_cast<const uint2*>(&sAT[k * PA + n0]);
      unsigned int wu = *reinterpret_cast<const unsigned int*>(&sW[kk * PW2 + j0b]);
      float av[4];
      bfquad(au.x, au.y, av);
      float w0 = __uint_as_float(wu << 16);
      float w1 = __uint_as_float(wu & 0xffff0000u);
#pragma unroll
      for (int ni = 0; ni < 4; ++ni) {
        acc2[ni][0] += av[ni] * w0;
        acc2[ni][1] += av[ni] * w1;
      }
    }
    __syncthreads();                  // before next chunk overwrites sW
  }

  // scorer epilogue: tanh(a+ab1) dot aw2 -> partial per (n, ty)
  {
    float sp[4] = {0.f, 0.f, 0.f, 0.f};
#pragma unroll
    for (int ni = 0; ni < 4; ++ni)
#pragma unroll
      for (int ji = 0; ji < 2; ++ji) {
        float aval = tanhf(acc2[ni][ji] + sAb1[j0b + ji]);
        sp[ni] += aval * sAw2[j0b + ji];
      }
#pragma unroll
    for (int ni = 0; ni < 4; ++ni) sPart[(n0 + ni) * PPART + ty] = sp[ni];
  }
  __syncthreads();

  // ---------------- P4: masked softmax over n (first wave) ----------------
  if (t < 64) {
    float logit = -INFINITY;
    bool valid = false;
    if (t < 32) {
      float s = sScal[1];
#pragma unroll
      for (int q = 0; q < 32; ++q) s += sPart[t * PPART + q];
      valid = (mask[((size_t)b * NN + t) * LL + l] != 0);   // int32 bool
      logit = valid ? s : -INFINITY;
    }
    float m = logit;
#pragma unroll
    for (int off = 32; off >= 1; off >>= 1) m = fmaxf(m, __shfl_xor(m, off));
    float e = (valid && m > -INFINITY) ? __expf(logit - m) : 0.0f;
    float ssum = e;
#pragma unroll
    for (int off = 32; off >= 1; off >>= 1) ssum += __shfl_xor(ssum, off);
    float at = (ssum > 0.0f) ? (e / ssum) : 0.0f;   // fully-masked row -> 0 (nan_to_num)
    if (t < 32) {
      sAttn[t] = at;
      outAT[((size_t)b * LL + l) * NN + t] = at;
    }
  }
  __syncthreads();

  // ---------------- P5: fused[d] = sum_n attn[n] * per_msg[n][d] ----------------
  {
    int d = t;                         // 256 threads == D
    float f = 0.0f;
#pragma unroll
    for (int n = 0; n < NN; ++n) f += sAttn[n] * bf2f(sAT[d * PA + n]);
    outF[(size_t)lb * DD + d] = f;
  }
}

extern "C" void kernel_launch(void* const* d_in, const int* in_sizes, int n_in,
                              void* d_out, int out_size, void* d_ws, size_t ws_size,
                              hipStream_t stream) {
  dynfusion_kernel<<<dim3(LL * BB), dim3(256), 0, stream>>>(
      (const float*)d_in[0],            // vert_feat
      (const float*)d_in[1],            // horiz_feat
      (const int*)d_in[2],              // mask_BNL bool (int32)
      (const float*)d_in[3],            // gw1
      (const float*)d_in[4],            // gb1
      (const float*)d_in[5],            // gw2
      (const float*)d_in[6],            // gb2
      (const float*)d_in[7],            // aw1
      (const float*)d_in[8],            // ab1
      (const float*)d_in[9],            // aw2
      (const float*)d_in[10],           // ab2
      (float*)d_out);
}